// Round 18
// baseline (193.924 us; speedup 1.0000x reference)
//
#include <hip/hip_runtime.h>
#include <hip/hip_bf16.h>

typedef _Float16 f16;
typedef _Float16 f16x4 __attribute__((ext_vector_type(4)));
typedef _Float16 f16x8 __attribute__((ext_vector_type(8)));
typedef float f32x4 __attribute__((ext_vector_type(4)));

constexpr int BATCH = 4, C = 512, CQ = 128, N = 4096;
constexpr int OALL = 768; // stacked outputs: f(128) + k(128) + v(512)

// workspace layout (bytes)
constexpr size_t WS_FT   = 0;                                      // f16 [B][N][128]       4 MB
constexpr size_t WS_KT   = WS_FT   + (size_t)BATCH * N * CQ * 2;   // f16 [B][N][128]       4 MB (K, row-major)
constexpr size_t WS_V    = WS_KT   + (size_t)BATCH * N * CQ * 2;   // f16 [B][C/16][N/8][16][8] 16 MB (tiled V)
constexpr size_t WS_WALL = WS_V    + (size_t)BATCH * C * N * 2;    // f16 [768][512]
constexpr size_t WS_BALL = WS_WALL + (size_t)OALL * C * 2;         // f32 [768]

// ---------------------------------------------------------------- stacked weights->fp16
__global__ void prep_weights(const float* __restrict__ Wf_w, const float* __restrict__ Wf_b,
                             const float* __restrict__ Wh_w, const float* __restrict__ Wh_b,
                             const float* __restrict__ Wl_w, const float* __restrict__ Wl_b,
                             f16* __restrict__ wall, float* __restrict__ ball) {
    int i = blockIdx.x * 256 + threadIdx.x;                 // grid covers 768*512
    if (i < OALL * C) {
        int o = i >> 9, c = i & 511;
        float v = (o < 128) ? Wf_w[o * C + c]
                : (o < 256) ? Wh_w[(o - 128) * C + c]
                            : Wl_w[(o - 256) * C + c];
        wall[i] = (f16)v;
    }
    if (i < OALL)
        ball[i] = (i < 128) ? Wf_b[i] : (i < 256) ? Wh_b[i - 128] : Wl_b[i - 256];
}

// ---------------------------------------------------------------- fused projections (v18: double-buffered staging)
// Block = 512 thr (8 waves), one (b, 64n) tile. Per 64-c chunk: stage x f32 ->
// LDS f16 transposed, DOUBLE-BUFFERED: issue chunk ch+1 global loads before the
// MFMA on chunk ch, write-late, one barrier per chunk (8 vs 16).
__global__ void __launch_bounds__(512) proj_all(const float* __restrict__ x, const f16* __restrict__ wall,
                                                const float* __restrict__ ball,
                                                f16* __restrict__ ft, f16* __restrict__ kt,
                                                f16* __restrict__ v) {
    __shared__ __align__(16) f16 xl[2][64][72];   // 18 KB
    const int tid = threadIdx.x;
    const int wv  = tid >> 6;
    const int lane = tid & 63;
    const int li = lane & 15, lg = lane >> 4;
    const int b  = blockIdx.x >> 6;
    const int n0 = (blockIdx.x & 63) * 64;
    const int ob = wv * 96;                    // wave's output slice (6 frags of 16)
    const int nn = tid & 63, cg = tid >> 6;    // staging decode: 8 c-groups of 8

    // prologue: stage chunk 0 -> xl[0]
    {
        const float* xs = x + ((size_t)(b * C) + cg * 8) * N + n0 + nn;
#pragma unroll
        for (int r = 0; r < 8; ++r)
            xl[0][nn][cg * 8 + r] = (f16)xs[(size_t)r * N];
    }
    __syncthreads();

    f32x4 acc[6][4] = {};                      // [o-frag][n-frag]
    for (int ch = 0; ch < 8; ++ch) {
        const int cur = ch & 1;
        // issue next chunk's global loads early (latency hides under MFMA)
        float xr[8];
        if (ch < 7) {
            const float* xs = x + ((size_t)(b * C) + (ch + 1) * 64 + cg * 8) * N + n0 + nn;
#pragma unroll
            for (int r = 0; r < 8; ++r) xr[r] = xs[(size_t)r * N];
        }
#pragma unroll
        for (int ks = 0; ks < 2; ++ks) {
            f16x8 xfr[4];
#pragma unroll
            for (int nf = 0; nf < 4; ++nf)
                xfr[nf] = *(const f16x8*)(&xl[cur][nf * 16 + li][ks * 32 + lg * 8]);
#pragma unroll
            for (int of = 0; of < 6; ++of) {
                f16x8 wfr = *(const f16x8*)(wall + (size_t)(ob + of * 16 + li) * C + ch * 64 + ks * 32 + lg * 8);
#pragma unroll
                for (int nf = 0; nf < 4; ++nf)
                    acc[of][nf] = __builtin_amdgcn_mfma_f32_16x16x32_f16(xfr[nf], wfr, acc[of][nf], 0, 0, 0);
            }
        }
        // write next chunk (other buffer; prev reads of that buffer done 1 chunk ago)
        if (ch < 7) {
#pragma unroll
            for (int r = 0; r < 8; ++r) xl[cur ^ 1][nn][cg * 8 + r] = (f16)xr[r];
        }
        __syncthreads();
    }
    // epilogue: D col(li) = o (B-operand row), D row (lg*4+r) = n (A-operand row)
#pragma unroll
    for (int of = 0; of < 6; ++of) {
        const int o = ob + of * 16 + li;
        const float bias = ball[o];
#pragma unroll
        for (int nf = 0; nf < 4; ++nf)
#pragma unroll
            for (int r = 0; r < 4; ++r) {
                const int n = n0 + nf * 16 + lg * 4 + r;
                const f16 val = (f16)(acc[of][nf][r] + bias);
                if (o < 128) {
                    ft[(size_t)(b * N + n) * CQ + o] = val;
                } else if (o < 256) {
                    const int ck = o - 128;
                    kt[((size_t)b * N + n) * 128 + ck] = val;
                } else {
                    const int c = o - 256;
                    v[(((size_t)b * 32 + (c >> 4)) * 512 + (n >> 3)) * 128 + (c & 15) * 8 + (n & 7)] = val;
                }
            }
    }
}

// ---------------------------------------------------------------- flash attention + residual (v18)
// v17 champion with the iteration ROTATED half a phase: QK(t+1) is computed
// right after PV(t) (both MFMA, co-scheduled; K from barrier-free register
// prefetch kfn), so the pre-B1 section is just max-tail + smax publish. exp(t)
// happens at loop top from s computed last iteration. Same 2 barriers, same
// hazard separations (pbuf: write post-B1 / read post-B2 pre-B1; smax: write
// post-B2 / read post-B1 pre-B2; ssum: write pre-B2 / read post-B2).
__global__ void __launch_bounds__(512, 2) attn(const f16* __restrict__ ft, const f16* __restrict__ kt,
                                               const f16* __restrict__ v,
                                               const float* __restrict__ x, const float* __restrict__ alphap,
                                               float* __restrict__ out) {
    __shared__ __align__(16) f16 pbuf[64 * 128];       // 16 KB shared P
    __shared__ float smax[8][4][16];
    __shared__ float ssum[8][4][16];

    const int tid  = threadIdx.x;
    const int wv   = tid >> 6;
    const int lane = tid & 63;
    const int li = lane & 15, lg = lane >> 4;
    const int swl = li & 7;
    // XCD-pinning: under blk%8 round-robin, each XCD sees a single batch
    const int v0 = blockIdx.x;
    const int b  = (v0 & 7) >> 1;
    const int it = ((v0 & 1) << 5) | (v0 >> 3);
    const int i0 = it * 64;
    const int c0 = wv * 64;

    // F fragments (B operand of swapped QK): col=i, k=ck; 4 i-frags
    f16x8 fb[4][4];
#pragma unroll
    for (int f = 0; f < 4; ++f) {
        const f16* fp = ft + (size_t)(b * N + i0 + f * 16 + li) * CQ + lg * 8;
#pragma unroll
        for (int ks = 0; ks < 4; ++ks) fb[f][ks] = *(const f16x8*)(fp + ks * 32);
    }

    // direct-register K: lane reads row (t*128 + wv*16 + li), cols ks*32 + lg*8
    const f16* kL = kt + ((size_t)b * N + wv * 16 + li) * 128 + lg * 8;
    // tiled V base: fragment (cf, phase) at vb2 + (cf*512 + t*16 + ph*4)*128
    const f16* vb2 = v + (((size_t)b * 32 + wv * 4) * 512 + lg) * 128 + li * 8;

    f32x4 oacc[4][4] = {};                       // [c-frag][i-frag]
    float ms[4] = {-1e30f, -1e30f, -1e30f, -1e30f};
    float ls[4] = {0.f, 0.f, 0.f, 0.f};

    // prologue: QK(0) from registers, publish smax(0), B1
    f32x4 s[4] = {};
    {
        f16x8 kf[4];
#pragma unroll
        for (int ks = 0; ks < 4; ++ks) kf[ks] = *(const f16x8*)(kL + ks * 32);
        __builtin_amdgcn_s_setprio(1);
#pragma unroll
        for (int ks = 0; ks < 4; ++ks)
#pragma unroll
            for (int f = 0; f < 4; ++f)
                s[f] = __builtin_amdgcn_mfma_f32_16x16x32_f16(kf[ks], fb[f][ks], s[f], 0, 0, 0);
        __builtin_amdgcn_s_setprio(0);
#pragma unroll
        for (int f = 0; f < 4; ++f) {
            float t0 = fmaxf(fmaxf(s[f][0], s[f][1]), fmaxf(s[f][2], s[f][3]));
            t0 = fmaxf(t0, __shfl_xor(t0, 16));
            t0 = fmaxf(t0, __shfl_xor(t0, 32));
            if (lane < 16) smax[wv][f][li] = t0;
        }
    }
    __syncthreads();   // B1(0): smax(0) visible

    for (int t = 0; t < 32; ++t) {
        const size_t jb0 = (size_t)t * 16;
        // prefetch K(t+1) fragments (registers, barrier-free, ~full-iter cover)
        f16x8 kfn[4];
        const size_t knext = (size_t)((t < 31) ? (t + 1) : 0) * 128 * 128;
#pragma unroll
        for (int ks = 0; ks < 4; ++ks) kfn[ks] = *(const f16x8*)(kL + knext + ks * 32);

        // (d) tile max over 8 waves (broadcast reads) + T13 deferred rescale
        float gm[4];
#pragma unroll
        for (int f = 0; f < 4; ++f) {
            float m0 = smax[0][f][li];
#pragma unroll
            for (int w = 1; w < 8; ++w) m0 = fmaxf(m0, smax[w][f][li]);
            gm[f] = m0;
        }
#pragma unroll
        for (int f = 0; f < 4; ++f) {
            if (!__all(gm[f] <= ms[f] + 8.0f)) {
                float mn = fmaxf(ms[f], gm[f]), sc = __expf(ms[f] - mn);
                ms[f] = mn; ls[f] *= sc;
#pragma unroll
                for (int cf = 0; cf < 4; ++cf) oacc[cf][f] *= sc;
            }
        }
        // (e) exp (this wave's 4 j per lane per f) + P write + partial sums
        const int jl = wv * 16 + lg * 4;
        const int gg = (jl >> 3) ^ swl;
        float ps[4];
#pragma unroll
        for (int f = 0; f < 4; ++f) {
            f16x4 pk;
            float p0 = 0.f;
#pragma unroll
            for (int r = 0; r < 4; ++r) { float p = __expf(s[f][r] - ms[f]); p0 += p; pk[r] = (f16)p; }
            *(f16x4*)(&pbuf[(f * 16 + li) * 128 + gg * 8 + (jl & 7)]) = pk;
            ps[f] = p0;
        }
#pragma unroll
        for (int f = 0; f < 4; ++f) {
            ps[f] += __shfl_xor(ps[f], 16);
            ps[f] += __shfl_xor(ps[f], 32);
        }
        if (lane < 16) {
#pragma unroll
            for (int f = 0; f < 4; ++f) ssum[wv][f][li] = ps[f];
        }
        // V prefetch phases 0,1 (latency hides under B2)
        f16x8 va[2][4];
#pragma unroll
        for (int cf = 0; cf < 4; ++cf) va[0][cf] = *(const f16x8*)(vb2 + ((size_t)cf * 512 + jb0) * 128);
#pragma unroll
        for (int cf = 0; cf < 4; ++cf) va[1][cf] = *(const f16x8*)(vb2 + ((size_t)cf * 512 + jb0 + 4) * 128);
        __syncthreads();   // B2: P + ssum visible
        // (f) accumulate l from shared partial sums
#pragma unroll
        for (int f = 0; f < 4; ++f) {
            float a0 = 0.f;
#pragma unroll
            for (int w = 0; w < 8; ++w) a0 += ssum[w][f][li];
            ls[f] += a0;
        }
        // (g) PV over full 128 j, this wave's 64 channels; rolling V prefetch
#pragma unroll
        for (int kf2 = 0; kf2 < 4; ++kf2) {
            const int cur = kf2 & 1;
            const int g = (kf2 * 4 + lg) ^ swl;
            f16x8 pb[4];
#pragma unroll
            for (int f = 0; f < 4; ++f)
                pb[f] = *(const f16x8*)(&pbuf[(f * 16 + li) * 128 + g * 8]);
            f16x8 vv0 = va[cur][0], vv1 = va[cur][1], vv2 = va[cur][2], vv3 = va[cur][3];
            if (kf2 < 2) {
#pragma unroll
                for (int cf = 0; cf < 4; ++cf)
                    va[cur][cf] = *(const f16x8*)(vb2 + ((size_t)cf * 512 + jb0 + (kf2 + 2) * 4) * 128);
            }
            __builtin_amdgcn_s_setprio(1);
#pragma unroll
            for (int f = 0; f < 4; ++f) {
                oacc[0][f] = __builtin_amdgcn_mfma_f32_16x16x32_f16(vv0, pb[f], oacc[0][f], 0, 0, 0);
                oacc[1][f] = __builtin_amdgcn_mfma_f32_16x16x32_f16(vv1, pb[f], oacc[1][f], 0, 0, 0);
                oacc[2][f] = __builtin_amdgcn_mfma_f32_16x16x32_f16(vv2, pb[f], oacc[2][f], 0, 0, 0);
                oacc[3][f] = __builtin_amdgcn_mfma_f32_16x16x32_f16(vv3, pb[f], oacc[3][f], 0, 0, 0);
            }
            __builtin_amdgcn_s_setprio(0);
        }
        // (h) QK(t+1) co-scheduled with PV tail (K from kfn, no barrier dep)
        if (t < 31) {
#pragma unroll
            for (int f = 0; f < 4; ++f) s[f] = (f32x4){0.f, 0.f, 0.f, 0.f};
            __builtin_amdgcn_s_setprio(1);
#pragma unroll
            for (int ks = 0; ks < 4; ++ks)
#pragma unroll
                for (int f = 0; f < 4; ++f)
                    s[f] = __builtin_amdgcn_mfma_f32_16x16x32_f16(kfn[ks], fb[f][ks], s[f], 0, 0, 0);
            __builtin_amdgcn_s_setprio(0);
            // max + publish smax(t+1); writes ordered after gm(t) reads by B2(t)
#pragma unroll
            for (int f = 0; f < 4; ++f) {
                float t0 = fmaxf(fmaxf(s[f][0], s[f][1]), fmaxf(s[f][2], s[f][3]));
                t0 = fmaxf(t0, __shfl_xor(t0, 16));
                t0 = fmaxf(t0, __shfl_xor(t0, 32));
                if (lane < 16) smax[wv][f][li] = t0;
            }
            __syncthreads();   // B1(t+1): pbuf reads done + smax visible
        }
    }

    // epilogue: O[c][i], i coalesced over li; + residual
    const float alpha = alphap[0];
#pragma unroll
    for (int f = 0; f < 4; ++f) {
        const float invf = alpha / ls[f];
        const float* xp = x + (size_t)(b * C + c0) * N + i0 + f * 16 + li;
        float* op = out + (size_t)(b * C + c0) * N + i0 + f * 16 + li;
#pragma unroll
        for (int cf = 0; cf < 4; ++cf)
#pragma unroll
            for (int r = 0; r < 4; ++r) {
                const int cl = cf * 16 + lg * 4 + r;
                op[(size_t)cl * N] = oacc[cf][f][r] * invf + xp[(size_t)cl * N];
            }
    }
}

extern "C" void kernel_launch(void* const* d_in, const int* in_sizes, int n_in,
                              void* d_out, int out_size, void* d_ws, size_t ws_size,
                              hipStream_t stream) {
    const float* x     = (const float*)d_in[0];
    const float* Wf_w  = (const float*)d_in[1];
    const float* Wf_b  = (const float*)d_in[2];
    const float* Wh_w  = (const float*)d_in[3];
    const float* Wh_b  = (const float*)d_in[4];
    const float* Wl_w  = (const float*)d_in[5];
    const float* Wl_b  = (const float*)d_in[6];
    const float* alpha = (const float*)d_in[7];
    char* ws = (char*)d_ws;
    f16*   ftb  = (f16*)(ws + WS_FT);
    f16*   ktb  = (f16*)(ws + WS_KT);
    f16*   vb   = (f16*)(ws + WS_V);
    f16*   wall = (f16*)(ws + WS_WALL);
    float* ball = (float*)(ws + WS_BALL);
    float* out  = (float*)d_out;

    prep_weights<<<dim3((OALL * C + 255) / 256), dim3(256), 0, stream>>>(Wf_w, Wf_b, Wh_w, Wh_b, Wl_w, Wl_b, wall, ball);
    // fused projections: 4 b x 64 n-tiles = 256 blocks x 8 waves, double-buffered
    proj_all<<<dim3(256), dim3(512), 0, stream>>>(x, wall, ball, ftb, ktb, vb);
    // 4 b x 64 query-tiles(64q) = 256 blocks x 8 waves = 1 block/CU, XCD-pinned
    attn<<<dim3(256), dim3(512), 0, stream>>>(ftb, ktb, vb, x, alpha, out);
}

// Round 19
// 168.295 us; speedup vs baseline: 1.1523x; 1.1523x over previous
//
#include <hip/hip_runtime.h>
#include <hip/hip_bf16.h>

typedef _Float16 f16;
typedef _Float16 f16x4 __attribute__((ext_vector_type(4)));
typedef _Float16 f16x8 __attribute__((ext_vector_type(8)));
typedef float f32x4 __attribute__((ext_vector_type(4)));

constexpr int BATCH = 4, C = 512, CQ = 128, N = 4096;
constexpr int OALL = 768; // stacked outputs: f(128) + k(128) + v(512)

// workspace layout (bytes)
constexpr size_t WS_FT   = 0;                                      // f16 [B][N][128]       4 MB
constexpr size_t WS_KT   = WS_FT   + (size_t)BATCH * N * CQ * 2;   // f16 [B][N][128]       4 MB (K, row-major)
constexpr size_t WS_V    = WS_KT   + (size_t)BATCH * N * CQ * 2;   // f16 [B][C/16][N/8][16][8] 16 MB (tiled V)
constexpr size_t WS_WALL = WS_V    + (size_t)BATCH * C * N * 2;    // f16 [768][512]
constexpr size_t WS_BALL = WS_WALL + (size_t)OALL * C * 2;         // f32 [768]

// ---------------------------------------------------------------- stacked weights->fp16
__global__ void prep_weights(const float* __restrict__ Wf_w, const float* __restrict__ Wf_b,
                             const float* __restrict__ Wh_w, const float* __restrict__ Wh_b,
                             const float* __restrict__ Wl_w, const float* __restrict__ Wl_b,
                             f16* __restrict__ wall, float* __restrict__ ball) {
    int i = blockIdx.x * 256 + threadIdx.x;                 // grid covers 768*512
    if (i < OALL * C) {
        int o = i >> 9, c = i & 511;
        float v = (o < 128) ? Wf_w[o * C + c]
                : (o < 256) ? Wh_w[(o - 128) * C + c]
                            : Wl_w[(o - 256) * C + c];
        wall[i] = (f16)v;
    }
    if (i < OALL)
        ball[i] = (i < 128) ? Wf_b[i] : (i < 256) ? Wh_b[i - 128] : Wl_b[i - 256];
}

// ---------------------------------------------------------------- fused projections (v16, unchanged champion)
__global__ void __launch_bounds__(512) proj_all(const float* __restrict__ x, const f16* __restrict__ wall,
                                                const float* __restrict__ ball,
                                                f16* __restrict__ ft, f16* __restrict__ kt,
                                                f16* __restrict__ v) {
    __shared__ __align__(16) f16 xl[64][72];   // 9 KB, 72-pad for b128 alignment
    const int tid = threadIdx.x;
    const int wv  = tid >> 6;
    const int lane = tid & 63;
    const int li = lane & 15, lg = lane >> 4;
    const int b  = blockIdx.x >> 6;
    const int n0 = (blockIdx.x & 63) * 64;
    const int ob = wv * 96;                    // wave's output slice (6 frags of 16)
    const int nn = tid & 63, cg = tid >> 6;    // staging decode: 8 c-groups of 8

    f32x4 acc[6][4] = {};                      // [o-frag][n-frag]
    for (int ch = 0; ch < 8; ++ch) {
        __syncthreads();                       // xl free (readers of prev chunk done)
        {   // stage 64c x 64n f32 -> xl[n][c] f16 (global reads coalesced along n)
            const float* xs = x + ((size_t)(b * C) + ch * 64 + cg * 8) * N + n0 + nn;
#pragma unroll
            for (int r = 0; r < 8; ++r)
                xl[nn][cg * 8 + r] = (f16)xs[(size_t)r * N];
        }
        __syncthreads();
#pragma unroll
        for (int ks = 0; ks < 2; ++ks) {
            f16x8 xfr[4];
#pragma unroll
            for (int nf = 0; nf < 4; ++nf)
                xfr[nf] = *(const f16x8*)(&xl[nf * 16 + li][ks * 32 + lg * 8]);
#pragma unroll
            for (int of = 0; of < 6; ++of) {
                f16x8 wfr = *(const f16x8*)(wall + (size_t)(ob + of * 16 + li) * C + ch * 64 + ks * 32 + lg * 8);
#pragma unroll
                for (int nf = 0; nf < 4; ++nf)
                    acc[of][nf] = __builtin_amdgcn_mfma_f32_16x16x32_f16(xfr[nf], wfr, acc[of][nf], 0, 0, 0);
            }
        }
    }
    // epilogue: D col(li) = o (B-operand row), D row (lg*4+r) = n (A-operand row)
#pragma unroll
    for (int of = 0; of < 6; ++of) {
        const int o = ob + of * 16 + li;
        const float bias = ball[o];
#pragma unroll
        for (int nf = 0; nf < 4; ++nf)
#pragma unroll
            for (int r = 0; r < 4; ++r) {
                const int n = n0 + nf * 16 + lg * 4 + r;
                const f16 val = (f16)(acc[of][nf][r] + bias);
                if (o < 128) {
                    ft[(size_t)(b * N + n) * CQ + o] = val;
                } else if (o < 256) {
                    const int ck = o - 128;
                    kt[((size_t)b * N + n) * 128 + ck] = val;
                } else {
                    const int c = o - 256;
                    v[(((size_t)b * 32 + (c >> 4)) * 512 + (n >> 3)) * 128 + (c & 15) * 8 + (n & 7)] = val;
                }
            }
    }
}

// ---------------------------------------------------------------- flash attention + residual (v19)
// = v17 champion (direct-register K double-buffer, 2 barriers, shared-stats
// softmax, rolling V prefetch) with ONE delta: stat arrays transposed to
// [f][li][8 waves] so the combine phases read 2x ds_read_b128 per frag
// instead of 8x ds_read_b32 (64 -> 16 LDS instr per lane per iter).
__global__ void __launch_bounds__(512, 2) attn(const f16* __restrict__ ft, const f16* __restrict__ kt,
                                               const f16* __restrict__ v,
                                               const float* __restrict__ x, const float* __restrict__ alphap,
                                               float* __restrict__ out) {
    __shared__ __align__(16) f16 pbuf[64 * 128];       // 16 KB shared P
    __shared__ __align__(16) float smax[4][16][8];     // [f][i(li)][wave]
    __shared__ __align__(16) float ssum[4][16][8];

    const int tid  = threadIdx.x;
    const int wv   = tid >> 6;
    const int lane = tid & 63;
    const int li = lane & 15, lg = lane >> 4;
    const int swl = li & 7;
    // XCD-pinning: under blk%8 round-robin, each XCD sees a single batch
    const int v0 = blockIdx.x;
    const int b  = (v0 & 7) >> 1;
    const int it = ((v0 & 1) << 5) | (v0 >> 3);
    const int i0 = it * 64;
    const int c0 = wv * 64;

    // F fragments (B operand of swapped QK): col=i, k=ck; 4 i-frags
    f16x8 fb[4][4];
#pragma unroll
    for (int f = 0; f < 4; ++f) {
        const f16* fp = ft + (size_t)(b * N + i0 + f * 16 + li) * CQ + lg * 8;
#pragma unroll
        for (int ks = 0; ks < 4; ++ks) fb[f][ks] = *(const f16x8*)(fp + ks * 32);
    }

    // direct-register K: lane reads row (t*128 + wv*16 + li), cols ks*32 + lg*8
    const f16* kL = kt + ((size_t)b * N + wv * 16 + li) * 128 + lg * 8;
    f16x8 kf[4];
#pragma unroll
    for (int ks = 0; ks < 4; ++ks) kf[ks] = *(const f16x8*)(kL + ks * 32);

    // tiled V base: fragment (cf, phase) at vb2 + (cf*512 + t*16 + ph*4)*128
    const f16* vb2 = v + (((size_t)b * 32 + wv * 4) * 512 + lg) * 128 + li * 8;
    f32x4 oacc[4][4] = {};                       // [c-frag][i-frag]
    float ms[4] = {-1e30f, -1e30f, -1e30f, -1e30f};
    float ls[4] = {0.f, 0.f, 0.f, 0.f};

    for (int t = 0; t < 32; ++t) {
        const size_t jb0 = (size_t)t * 16;
        // (a) prefetch next K tile fragments into kfn (whole iteration of cover)
        f16x8 kfn[4];
        const size_t knext = (size_t)((t < 31) ? (t + 1) : 0) * 128 * 128;
#pragma unroll
        for (int ks = 0; ks < 4; ++ks) kfn[ks] = *(const f16x8*)(kL + knext + ks * 32);

        // (b) QK for this wave's 16-j slice, all 4 i-frags (K from registers)
        f32x4 s[4] = {};
        __builtin_amdgcn_s_setprio(1);
#pragma unroll
        for (int ks = 0; ks < 4; ++ks)
#pragma unroll
            for (int f = 0; f < 4; ++f)
                s[f] = __builtin_amdgcn_mfma_f32_16x16x32_f16(kf[ks], fb[f][ks], s[f], 0, 0, 0);
        __builtin_amdgcn_s_setprio(0);

        // (c) wave-local max per query (rows j = wv*16 + lg*4 + r)
#pragma unroll
        for (int f = 0; f < 4; ++f) {
            float t0 = fmaxf(fmaxf(s[f][0], s[f][1]), fmaxf(s[f][2], s[f][3]));
            t0 = fmaxf(t0, __shfl_xor(t0, 16));
            t0 = fmaxf(t0, __shfl_xor(t0, 32));
            if (lane < 16) smax[f][li][wv] = t0;
        }
        // V prefetch for PV kf=0, issued before the barrier (latency hides under it)
        f16x8 va[2][4];
#pragma unroll
        for (int cf = 0; cf < 4; ++cf) va[0][cf] = *(const f16x8*)(vb2 + ((size_t)cf * 512 + jb0) * 128);
        __syncthreads();   // B1: max stats visible
        // (d) tile max over 8 waves: vectorized b128 reads
        float gm[4];
#pragma unroll
        for (int f = 0; f < 4; ++f) {
            f32x4 a0 = *(const f32x4*)(&smax[f][li][0]);
            f32x4 a1 = *(const f32x4*)(&smax[f][li][4]);
            float m0 = fmaxf(fmaxf(fmaxf(a0[0], a0[1]), fmaxf(a0[2], a0[3])),
                             fmaxf(fmaxf(a1[0], a1[1]), fmaxf(a1[2], a1[3])));
            gm[f] = m0;
        }
        // V prefetch for kf=1
#pragma unroll
        for (int cf = 0; cf < 4; ++cf) va[1][cf] = *(const f16x8*)(vb2 + ((size_t)cf * 512 + jb0 + 4) * 128);
        // T13 deferred rescale (identical decision in all waves: shared stats)
#pragma unroll
        for (int f = 0; f < 4; ++f) {
            if (!__all(gm[f] <= ms[f] + 8.0f)) {
                float mn = fmaxf(ms[f], gm[f]), sc = __expf(ms[f] - mn);
                ms[f] = mn; ls[f] *= sc;
#pragma unroll
                for (int cf = 0; cf < 4; ++cf) oacc[cf][f] *= sc;
            }
        }
        // exp (this wave's 4 j per lane per f) + P write + partial sums
        const int jl = wv * 16 + lg * 4;
        const int gg = (jl >> 3) ^ swl;
        float ps[4];
#pragma unroll
        for (int f = 0; f < 4; ++f) {
            f16x4 pk;
            float p0 = 0.f;
#pragma unroll
            for (int r = 0; r < 4; ++r) { float p = __expf(s[f][r] - ms[f]); p0 += p; pk[r] = (f16)p; }
            *(f16x4*)(&pbuf[(f * 16 + li) * 128 + gg * 8 + (jl & 7)]) = pk;
            ps[f] = p0;
        }
#pragma unroll
        for (int f = 0; f < 4; ++f) {
            ps[f] += __shfl_xor(ps[f], 16);
            ps[f] += __shfl_xor(ps[f], 32);
        }
        if (lane < 16) {
#pragma unroll
            for (int f = 0; f < 4; ++f) ssum[f][li][wv] = ps[f];
        }
        __syncthreads();   // B2: P + ssum visible
        // (f) accumulate l: vectorized b128 reads
#pragma unroll
        for (int f = 0; f < 4; ++f) {
            f32x4 a0 = *(const f32x4*)(&ssum[f][li][0]);
            f32x4 a1 = *(const f32x4*)(&ssum[f][li][4]);
            ls[f] += (a0[0] + a0[1] + a0[2] + a0[3]) + (a1[0] + a1[1] + a1[2] + a1[3]);
        }
        // (g) PV over full 128 j, this wave's 64 channels; rolling V prefetch
#pragma unroll
        for (int kf2 = 0; kf2 < 4; ++kf2) {
            const int cur = kf2 & 1;
            const int g = (kf2 * 4 + lg) ^ swl;
            f16x8 pb[4];
#pragma unroll
            for (int f = 0; f < 4; ++f)
                pb[f] = *(const f16x8*)(&pbuf[(f * 16 + li) * 128 + g * 8]);
            f16x8 vv0 = va[cur][0], vv1 = va[cur][1], vv2 = va[cur][2], vv3 = va[cur][3];
            if (kf2 < 2) {
#pragma unroll
                for (int cf = 0; cf < 4; ++cf)
                    va[cur][cf] = *(const f16x8*)(vb2 + ((size_t)cf * 512 + jb0 + (kf2 + 2) * 4) * 128);
            }
            __builtin_amdgcn_s_setprio(1);
#pragma unroll
            for (int f = 0; f < 4; ++f) {
                oacc[0][f] = __builtin_amdgcn_mfma_f32_16x16x32_f16(vv0, pb[f], oacc[0][f], 0, 0, 0);
                oacc[1][f] = __builtin_amdgcn_mfma_f32_16x16x32_f16(vv1, pb[f], oacc[1][f], 0, 0, 0);
                oacc[2][f] = __builtin_amdgcn_mfma_f32_16x16x32_f16(vv2, pb[f], oacc[2][f], 0, 0, 0);
                oacc[3][f] = __builtin_amdgcn_mfma_f32_16x16x32_f16(vv3, pb[f], oacc[3][f], 0, 0, 0);
            }
            __builtin_amdgcn_s_setprio(0);
        }
        // roll K double-buffer
#pragma unroll
        for (int ks = 0; ks < 4; ++ks) kf[ks] = kfn[ks];
        // no 3rd barrier: next iter's B1 orders pbuf reuse (same proof as v12)
    }

    // epilogue: O[c][i], i coalesced over li; + residual
    const float alpha = alphap[0];
#pragma unroll
    for (int f = 0; f < 4; ++f) {
        const float invf = alpha / ls[f];
        const float* xp = x + (size_t)(b * C + c0) * N + i0 + f * 16 + li;
        float* op = out + (size_t)(b * C + c0) * N + i0 + f * 16 + li;
#pragma unroll
        for (int cf = 0; cf < 4; ++cf)
#pragma unroll
            for (int r = 0; r < 4; ++r) {
                const int cl = cf * 16 + lg * 4 + r;
                op[(size_t)cl * N] = oacc[cf][f][r] * invf + xp[(size_t)cl * N];
            }
    }
}

extern "C" void kernel_launch(void* const* d_in, const int* in_sizes, int n_in,
                              void* d_out, int out_size, void* d_ws, size_t ws_size,
                              hipStream_t stream) {
    const float* x     = (const float*)d_in[0];
    const float* Wf_w  = (const float*)d_in[1];
    const float* Wf_b  = (const float*)d_in[2];
    const float* Wh_w  = (const float*)d_in[3];
    const float* Wh_b  = (const float*)d_in[4];
    const float* Wl_w  = (const float*)d_in[5];
    const float* Wl_b  = (const float*)d_in[6];
    const float* alpha = (const float*)d_in[7];
    char* ws = (char*)d_ws;
    f16*   ftb  = (f16*)(ws + WS_FT);
    f16*   ktb  = (f16*)(ws + WS_KT);
    f16*   vb   = (f16*)(ws + WS_V);
    f16*   wall = (f16*)(ws + WS_WALL);
    float* ball = (float*)(ws + WS_BALL);
    float* out  = (float*)d_out;

    prep_weights<<<dim3((OALL * C + 255) / 256), dim3(256), 0, stream>>>(Wf_w, Wf_b, Wh_w, Wh_b, Wl_w, Wl_b, wall, ball);
    // fused projections: 4 b x 64 n-tiles = 256 blocks x 8 waves
    proj_all<<<dim3(256), dim3(512), 0, stream>>>(x, wall, ball, ftb, ktb, vb);
    // 4 b x 64 query-tiles(64q) = 256 blocks x 8 waves = 1 block/CU, XCD-pinned
    attn<<<dim3(256), dim3(512), 0, stream>>>(ftb, ktb, vb, x, alpha, out);
}